// Round 18
// baseline (2199.112 us; speedup 1.0000x reference)
//
#include <hip/hip_runtime.h>

typedef unsigned int uint32;
typedef unsigned short ushort16;
typedef __attribute__((ext_vector_type(16))) float f32x16;
typedef __attribute__((ext_vector_type(8)))  short short8;

#define THREADS 256
#define QB 128      // A-rows per block (4 waves x 32)
#define SLICE 1024  // B-points per block (32 tiles, staged once: 32 KB LDS)
#define RB 128      // reduce stage-1 blocks

__device__ inline ushort16 bf16rn(float x) {
    uint32 u = __float_as_uint(x);
    u += 0x7FFFu + ((u >> 16) & 1u);
    return (ushort16)(u >> 16);
}
__device__ inline float bf2f(ushort16 h) { return __uint_as_float(((uint32)h) << 16); }

// K=16 slot map (verified R11-R17). Row side (A): per coord [h,h,m,m];
// slots 12..14 = 1. Col side (B): per coord [bh,bm,bh,bm] of b=-2c; slots
// 12..14 = 3-level split of |b|^2. C-operand carries |a|^2 =>
// D = |a|^2 + |b|^2 - 2 a.b -> row-min AND col-min both valid, one matrix.
// Pad A rows: a2=1e30 (never win col-min). Pad B cols: s12=1e30 sentinel.
__global__ __launch_bounds__(THREADS) void cd_prep(
    const float* __restrict__ A, int n, int padN,
    const float* __restrict__ B, int m, int padM,
    short8* __restrict__ Qf, float* __restrict__ a2,
    short8* __restrict__ Sf, uint32* __restrict__ bits)
{
    const int i = blockIdx.x * THREADS + threadIdx.x;
    if (i < n + m) bits[i] = 0x7F800000u;  // +inf

    if (i < padN) {  // row side
        ushort16 qs[16];
#pragma unroll
        for (int s = 0; s < 16; ++s) qs[s] = 0;
        float w = 1e30f;
        if (i < n) {
            float c[3] = {A[3*i], A[3*i+1], A[3*i+2]};
            w = fmaf(c[0], c[0], fmaf(c[1], c[1], c[2]*c[2]));
#pragma unroll
            for (int cc = 0; cc < 3; ++cc) {
                ushort16 h = bf16rn(c[cc]);
                ushort16 md = bf16rn(c[cc] - bf2f(h));
                const int b = 4*cc;
                qs[b]=h; qs[b+1]=h; qs[b+2]=md; qs[b+3]=md;
            }
            qs[12]=0x3F80; qs[13]=0x3F80; qs[14]=0x3F80;
        }
        a2[i] = w;
        const int row = i & 31, grp = i >> 5;
#pragma unroll
        for (int h = 0; h < 2; ++h) {
            short8 qv;
#pragma unroll
            for (int e = 0; e < 8; ++e) qv[e] = (short)qs[8*h+e];
            Qf[(size_t)grp*64 + h*32 + row] = qv;
        }
    }
    if (i < padM) {  // col side
        ushort16 ss[16];
#pragma unroll
        for (int s = 0; s < 16; ++s) ss[s] = 0;
        if (i < m) {
            float c[3] = {B[3*i], B[3*i+1], B[3*i+2]};
            float w = fmaf(c[0], c[0], fmaf(c[1], c[1], c[2]*c[2]));
#pragma unroll
            for (int cc = 0; cc < 3; ++cc) {
                float bv = -2.f * c[cc];
                ushort16 bh = bf16rn(bv);
                ushort16 bm = bf16rn(bv - bf2f(bh));
                const int b = 4*cc;
                ss[b]=bh; ss[b+1]=bm; ss[b+2]=bh; ss[b+3]=bm;
            }
            ushort16 wh = bf16rn(w);
            float r1 = w - bf2f(wh);
            ushort16 wm = bf16rn(r1);
            ushort16 wl = bf16rn(r1 - bf2f(wm));
            ss[12]=wh; ss[13]=wm; ss[14]=wl;
        } else {
            ss[12] = bf16rn(1e30f);
        }
        const int row = i & 31, grp = i >> 5;
#pragma unroll
        for (int h = 0; h < 2; ++h) {
            short8 sv;
#pragma unroll
            for (int e = 0; e < 8; ++e) sv[e] = (short)ss[8*h+e];
            Sf[(size_t)grp*64 + h*32 + row] = sv;
        }
    }
}

__device__ inline float dppmin(float v, int ctrl) {
    float s;
    switch (ctrl) {
        case 0xB1:  s = __int_as_float(__builtin_amdgcn_mov_dpp(__float_as_int(v), 0xB1,  0xf, 0xf, false)); break; // xor1
        case 0x4E:  s = __int_as_float(__builtin_amdgcn_mov_dpp(__float_as_int(v), 0x4E,  0xf, 0xf, false)); break; // xor2
        case 0x141: s = __int_as_float(__builtin_amdgcn_mov_dpp(__float_as_int(v), 0x141, 0xf, 0xf, false)); break; // half_mirror
        default:    s = __int_as_float(__builtin_amdgcn_mov_dpp(__float_as_int(v), 0x140, 0xf, 0xf, false)); break; // row_mirror
    }
    return fminf(v, s);
}

// min of 16 regs via min3 tree (~8 ops)
__device__ inline float tmin16(const f32x16& c) {
    float a0 = fminf(fminf(c[0], c[1]), c[2]);
    float a1 = fminf(fminf(c[3], c[4]), c[5]);
    float a2_ = fminf(fminf(c[6], c[7]), c[8]);
    float a3 = fminf(fminf(c[9], c[10]), c[11]);
    float a4 = fminf(fminf(c[12], c[13]), c[14]);
    float b0 = fminf(fminf(a0, a1), c[15]);
    float b1 = fminf(fminf(a2_, a3), a4);
    return fminf(b0, b1);
}

// ONE-PASS chamfer, register-resident col-min. Block (ib, js): 128 A-rows vs
// 1024 B-points, staged ONCE in 32 KB LDS (single barrier). 32 fully-unrolled
// tiles: 1 ds_read_b128 + 1 MFMA + 8 min3 (row fold) + tmin16 (col fold into
// static cm[t]). End: row-min butterfly -> atomicMin(bits[row]); col-min
// xor32 + plain-LDS cross-wave combine (reusing sb) -> atomicMin(bits[n+col]).
// All atomics on float bits of clamped non-negative values => deterministic.
// C layout (m74/m101): col=lane&31, row=(reg&3)+8*(reg>>2)+4*(lane>>5).
__global__ __launch_bounds__(THREADS, 4) void cd_mfma(
    const short8* __restrict__ Qf, const float* __restrict__ a2, int padN, int n,
    const short8* __restrict__ Sf, int padM, int m,
    uint32* __restrict__ bits)
{
    __shared__ short8 sb[SLICE * 2];   // 32 KB

    const int ib = blockIdx.x, js = blockIdx.y;
    const int tid = threadIdx.x, lane = tid & 63, wid = tid >> 6;
    const int qbase = ib * QB + wid * 32;

    const short8 av = Qf[(size_t)(qbase >> 5) * 64 + lane];

    f32x16 pc;
    {
        const int rb = qbase + 4 * (lane >> 5);
#pragma unroll
        for (int r = 0; r < 16; ++r) pc[r] = a2[rb + (r & 3) + 8 * (r >> 2)];
    }

    // stage the whole slice (2048 short8, 8 per thread), one barrier
    {
        const size_t gb = (size_t)js * (SLICE * 2);
#pragma unroll
        for (int k = 0; k < 8; ++k)
            sb[k * 256 + tid] = Sf[gb + k * 256 + tid];
    }
    __syncthreads();

    float rmin[16];
#pragma unroll
    for (int r = 0; r < 16; ++r) rmin[r] = 1e30f;
    float cm[32];

#pragma unroll
    for (int g = 0; g < 16; ++g) {
        const short8 b0 = sb[(2*g)   * 64 + lane];
        const short8 b1 = sb[(2*g+1) * 64 + lane];
        const f32x16 c0 = __builtin_amdgcn_mfma_f32_32x32x16_bf16(av, b0, pc, 0, 0, 0);
        const f32x16 c1 = __builtin_amdgcn_mfma_f32_32x32x16_bf16(av, b1, pc, 0, 0, 0);
#pragma unroll
        for (int r = 0; r < 16; ++r)
            rmin[r] = fminf(fminf(rmin[r], c0[r]), c1[r]);  // v_min3
        cm[2*g]   = tmin16(c0);
        cm[2*g+1] = tmin16(c1);
    }

    // row-min: butterfly over the 32 cols held across lanes
#pragma unroll
    for (int r = 0; r < 16; ++r) {
        float v = rmin[r];
        v = dppmin(v, 0xB1);
        v = dppmin(v, 0x4E);
        v = dppmin(v, 0x141);
        v = dppmin(v, 0x140);
        v = fminf(v, __shfl_xor(v, 16, 64));
        rmin[r] = v;
    }
    if ((lane & 31) == 0) {
        const int rb = qbase + 4 * (lane >> 5);
#pragma unroll
        for (int r = 0; r < 16; ++r) {
            const int qi = rb + (r & 3) + 8 * (r >> 2);
            if (qi < n)
                atomicMin(&bits[qi], __float_as_uint(fmaxf(rmin[r], 0.f)));
        }
    }

    // col-min: combine lane halves (rows 0-15 vs 16-31 of the wave's frag)
#pragma unroll
    for (int t = 0; t < 32; ++t)
        cm[t] = fminf(cm[t], __shfl_xor(cm[t], 32, 64));

    __syncthreads();                    // done reading sb -> reuse as float
    float* sbf = (float*)sb;            // [4][SLICE]
    if (lane < 32) {
#pragma unroll
        for (int t = 0; t < 32; ++t)
            sbf[wid * SLICE + t * 32 + lane] = cm[t];
    }
    __syncthreads();

#pragma unroll
    for (int u = 0; u < SLICE / THREADS; ++u) {
        const int c = u * THREADS + tid;
        float v = fminf(fminf(sbf[c], sbf[SLICE + c]),
                        fminf(sbf[2*SLICE + c], sbf[3*SLICE + c]));
        const int cj = js * SLICE + c;
        if (cj < m)
            atomicMin(&bits[n + cj], __float_as_uint(fmaxf(v, 0.f)));
    }
}

__global__ __launch_bounds__(THREADS) void cd_reduce1(
    const uint32* __restrict__ bits, int count, double* __restrict__ partials)
{
    double s = 0.0;
    for (int i = blockIdx.x * THREADS + threadIdx.x; i < count; i += gridDim.x * THREADS)
        s += (double)sqrtf(__uint_as_float(bits[i]));
#pragma unroll
    for (int off = 32; off; off >>= 1) s += __shfl_down(s, off, 64);
    __shared__ double sw[4];
    const int lane = threadIdx.x & 63, wid = threadIdx.x >> 6;
    if (lane == 0) sw[wid] = s;
    __syncthreads();
    if (threadIdx.x == 0) partials[blockIdx.x] = sw[0] + sw[1] + sw[2] + sw[3];
}

__global__ __launch_bounds__(THREADS) void cd_reduce2(
    const double* __restrict__ partials, int nb, int total, float* __restrict__ out)
{
    double s = 0.0;
    for (int i = threadIdx.x; i < nb; i += THREADS) s += partials[i];
#pragma unroll
    for (int off = 32; off; off >>= 1) s += __shfl_down(s, off, 64);
    __shared__ double sw[4];
    const int lane = threadIdx.x & 63, wid = threadIdx.x >> 6;
    if (lane == 0) sw[wid] = s;
    __syncthreads();
    if (threadIdx.x == 0)
        out[0] = (float)((sw[0] + sw[1] + sw[2] + sw[3]) / (double)total);
}

extern "C" void kernel_launch(void* const* d_in, const int* in_sizes, int n_in,
                              void* d_out, int out_size, void* d_ws, size_t ws_size,
                              hipStream_t stream) {
    const float* a = (const float*)d_in[0];
    const float* b = (const float*)d_in[1];
    const int n = in_sizes[0] / 3;
    const int m = in_sizes[1] / 3;
    const int total = n + m;
    float* out = (float*)d_out;

    const int padN = (n + QB - 1) / QB * QB;
    const int padM = (m + SLICE - 1) / SLICE * SLICE;
    const int gx  = padN / QB;
    const int nJS = padM / SLICE;

    // ws: Qf | a2 | Sf | bits | partials
    char* wp = (char*)d_ws;
    short8* Qf = (short8*)wp;    wp += (size_t)padN * 32;
    float*  a2 = (float*)wp;     wp += (size_t)padN * 4;
    short8* Sf = (short8*)wp;    wp += (size_t)padM * 32;
    uint32* bits = (uint32*)wp;  wp += (size_t)total * 4;
    wp = (char*)(((size_t)wp + 255) & ~(size_t)255);
    double* partials = (double*)wp;

    const int prepElems = max(max(padN, padM), total);
    cd_prep<<<(prepElems + THREADS - 1) / THREADS, THREADS, 0, stream>>>(
        a, n, padN, b, m, padM, Qf, a2, Sf, bits);

    dim3 grid(gx, nJS);
    cd_mfma<<<grid, THREADS, 0, stream>>>(Qf, a2, padN, n, Sf, padM, m, bits);

    cd_reduce1<<<RB, THREADS, 0, stream>>>(bits, total, partials);
    cd_reduce2<<<1, THREADS, 0, stream>>>(partials, RB, total, out);
}

// Round 19
// 233.553 us; speedup vs baseline: 9.4159x; 9.4159x over previous
//
#include <hip/hip_runtime.h>

typedef unsigned int uint32;
typedef unsigned short ushort16;
typedef __attribute__((ext_vector_type(16))) float f32x16;
typedef __attribute__((ext_vector_type(8)))  short short8;

#define THREADS 256
#define QB 128      // A-rows per block (4 waves x 32)
#define SLICE 512   // B-points per block (16 tiles; 16 KB staging + 8 KB cmlds)
#define RB 128      // reduce stage-1 blocks

__device__ inline ushort16 bf16rn(float x) {
    uint32 u = __float_as_uint(x);
    u += 0x7FFFu + ((u >> 16) & 1u);
    return (ushort16)(u >> 16);
}
__device__ inline float bf2f(ushort16 h) { return __uint_as_float(((uint32)h) << 16); }

// K=16 slot map (verified R11-R18). Row side (A): per coord [h,h,m,m];
// slots 12..14 = 1. Col side (B): per coord [bh,bm,bh,bm] of b=-2c; slots
// 12..14 = 3-level split of |b|^2. C-operand carries |a|^2 =>
// D = |a|^2 + |b|^2 - 2 a.b -> row-min AND col-min both valid, one matrix.
// Pad A rows: a2=1e30 (never win col-min). Pad B cols: s12=1e30 sentinel.
__global__ __launch_bounds__(THREADS) void cd_prep(
    const float* __restrict__ A, int n, int padN,
    const float* __restrict__ B, int m, int padM,
    short8* __restrict__ Qf, float* __restrict__ a2,
    short8* __restrict__ Sf, uint32* __restrict__ bits)
{
    const int i = blockIdx.x * THREADS + threadIdx.x;
    if (i < n + m) bits[i] = 0x7F800000u;  // +inf

    if (i < padN) {  // row side
        ushort16 qs[16];
#pragma unroll
        for (int s = 0; s < 16; ++s) qs[s] = 0;
        float w = 1e30f;
        if (i < n) {
            float c[3] = {A[3*i], A[3*i+1], A[3*i+2]};
            w = fmaf(c[0], c[0], fmaf(c[1], c[1], c[2]*c[2]));
#pragma unroll
            for (int cc = 0; cc < 3; ++cc) {
                ushort16 h = bf16rn(c[cc]);
                ushort16 md = bf16rn(c[cc] - bf2f(h));
                const int b = 4*cc;
                qs[b]=h; qs[b+1]=h; qs[b+2]=md; qs[b+3]=md;
            }
            qs[12]=0x3F80; qs[13]=0x3F80; qs[14]=0x3F80;
        }
        a2[i] = w;
        const int row = i & 31, grp = i >> 5;
#pragma unroll
        for (int h = 0; h < 2; ++h) {
            short8 qv;
#pragma unroll
            for (int e = 0; e < 8; ++e) qv[e] = (short)qs[8*h+e];
            Qf[(size_t)grp*64 + h*32 + row] = qv;
        }
    }
    if (i < padM) {  // col side
        ushort16 ss[16];
#pragma unroll
        for (int s = 0; s < 16; ++s) ss[s] = 0;
        if (i < m) {
            float c[3] = {B[3*i], B[3*i+1], B[3*i+2]};
            float w = fmaf(c[0], c[0], fmaf(c[1], c[1], c[2]*c[2]));
#pragma unroll
            for (int cc = 0; cc < 3; ++cc) {
                float bv = -2.f * c[cc];
                ushort16 bh = bf16rn(bv);
                ushort16 bm = bf16rn(bv - bf2f(bh));
                const int b = 4*cc;
                ss[b]=bh; ss[b+1]=bm; ss[b+2]=bh; ss[b+3]=bm;
            }
            ushort16 wh = bf16rn(w);
            float r1 = w - bf2f(wh);
            ushort16 wm = bf16rn(r1);
            ushort16 wl = bf16rn(r1 - bf2f(wm));
            ss[12]=wh; ss[13]=wm; ss[14]=wl;
        } else {
            ss[12] = bf16rn(1e30f);
        }
        const int row = i & 31, grp = i >> 5;
#pragma unroll
        for (int h = 0; h < 2; ++h) {
            short8 sv;
#pragma unroll
            for (int e = 0; e < 8; ++e) sv[e] = (short)ss[8*h+e];
            Sf[(size_t)grp*64 + h*32 + row] = sv;
        }
    }
}

__device__ inline float dppmin(float v, int ctrl) {
    float s;
    switch (ctrl) {
        case 0xB1:  s = __int_as_float(__builtin_amdgcn_mov_dpp(__float_as_int(v), 0xB1,  0xf, 0xf, false)); break; // xor1
        case 0x4E:  s = __int_as_float(__builtin_amdgcn_mov_dpp(__float_as_int(v), 0x4E,  0xf, 0xf, false)); break; // xor2
        case 0x141: s = __int_as_float(__builtin_amdgcn_mov_dpp(__float_as_int(v), 0x141, 0xf, 0xf, false)); break; // half_mirror
        default:    s = __int_as_float(__builtin_amdgcn_mov_dpp(__float_as_int(v), 0x140, 0xf, 0xf, false)); break; // row_mirror
    }
    return fminf(v, s);
}

// min of 16 regs via min3 tree (~8 ops)
__device__ inline float tmin16(const f32x16& c) {
    float a0 = fminf(fminf(c[0], c[1]), c[2]);
    float a1 = fminf(fminf(c[3], c[4]), c[5]);
    float a2_ = fminf(fminf(c[6], c[7]), c[8]);
    float a3 = fminf(fminf(c[9], c[10]), c[11]);
    float a4 = fminf(fminf(c[12], c[13]), c[14]);
    float b0 = fminf(fminf(a0, a1), c[15]);
    float b1 = fminf(fminf(a2_, a3), a4);
    return fminf(b0, b1);
}

// ONE-PASS chamfer, ZERO-REGISTER col-min (R18's cm[32] spilled; this streams
// each tile's col-min straight to LDS). Block (ib, js): 128 A-rows x 512
// B-points staged once. Per tile: MFMA -> 8 min3 row-fold -> tmin16 ->
// xor32 shuffle -> plain LDS store cmlds[wid][t*32+col] (unique addr, no
// atomics). End: row butterfly -> atomicMin(bits[row]); barrier; 4-way min
// over wave rows -> atomicMin(bits[n+col]). All atomic values clamped >= 0
// => bit-ordered atomicMin is exact & deterministic.
// C layout (m74/m101): col=lane&31, row=(reg&3)+8*(reg>>2)+4*(lane>>5).
__global__ __launch_bounds__(THREADS, 4) void cd_mfma(
    const short8* __restrict__ Qf, const float* __restrict__ a2, int padN, int n,
    const short8* __restrict__ Sf, int padM, int m,
    uint32* __restrict__ bits)
{
    __shared__ short8 sb[SLICE * 2];        // 16 KB staging
    __shared__ float cmlds[4 * SLICE];      // 8 KB per-wave col-mins

    const int ib = blockIdx.x, js = blockIdx.y;
    const int tid = threadIdx.x, lane = tid & 63, wid = tid >> 6;
    const int qbase = ib * QB + wid * 32;

    const short8 av = Qf[(size_t)(qbase >> 5) * 64 + lane];

    f32x16 pc;
    {
        const int rb = qbase + 4 * (lane >> 5);
#pragma unroll
        for (int r = 0; r < 16; ++r) pc[r] = a2[rb + (r & 3) + 8 * (r >> 2)];
    }

    // stage the slice (1024 short8, 4 per thread), one barrier
    {
        const size_t gb = (size_t)js * (SLICE * 2);
#pragma unroll
        for (int k = 0; k < 4; ++k)
            sb[k * 256 + tid] = Sf[gb + k * 256 + tid];
    }
    __syncthreads();

    float rmin[16];
#pragma unroll
    for (int r = 0; r < 16; ++r) rmin[r] = 1e30f;

    float* myrow = cmlds + wid * SLICE + (lane & 31);
    const bool lo = (lane < 32);

#pragma unroll
    for (int g = 0; g < 8; ++g) {
        const short8 b0 = sb[(2*g)   * 64 + lane];
        const short8 b1 = sb[(2*g+1) * 64 + lane];
        const f32x16 c0 = __builtin_amdgcn_mfma_f32_32x32x16_bf16(av, b0, pc, 0, 0, 0);
        const f32x16 c1 = __builtin_amdgcn_mfma_f32_32x32x16_bf16(av, b1, pc, 0, 0, 0);
#pragma unroll
        for (int r = 0; r < 16; ++r)
            rmin[r] = fminf(fminf(rmin[r], c0[r]), c1[r]);  // v_min3
        float v0 = tmin16(c0);
        float v1 = tmin16(c1);
        v0 = fminf(v0, __shfl_xor(v0, 32, 64));
        v1 = fminf(v1, __shfl_xor(v1, 32, 64));
        if (lo) {
            myrow[(2*g)   * 32] = v0;
            myrow[(2*g+1) * 32] = v1;
        }
    }

    // row-min: butterfly over the 32 cols held across lanes
#pragma unroll
    for (int r = 0; r < 16; ++r) {
        float v = rmin[r];
        v = dppmin(v, 0xB1);
        v = dppmin(v, 0x4E);
        v = dppmin(v, 0x141);
        v = dppmin(v, 0x140);
        v = fminf(v, __shfl_xor(v, 16, 64));
        rmin[r] = v;
    }
    if ((lane & 31) == 0) {
        const int rb = qbase + 4 * (lane >> 5);
#pragma unroll
        for (int r = 0; r < 16; ++r) {
            const int qi = rb + (r & 3) + 8 * (r >> 2);
            if (qi < n)
                atomicMin(&bits[qi], __float_as_uint(fmaxf(rmin[r], 0.f)));
        }
    }

    __syncthreads();   // all cmlds writes visible

#pragma unroll
    for (int u = 0; u < SLICE / THREADS; ++u) {
        const int c = u * THREADS + tid;
        const float v = fminf(fminf(cmlds[c], cmlds[SLICE + c]),
                              fminf(cmlds[2*SLICE + c], cmlds[3*SLICE + c]));
        const int cj = js * SLICE + c;
        if (cj < m)
            atomicMin(&bits[n + cj], __float_as_uint(fmaxf(v, 0.f)));
    }
}

__global__ __launch_bounds__(THREADS) void cd_reduce1(
    const uint32* __restrict__ bits, int count, double* __restrict__ partials)
{
    double s = 0.0;
    for (int i = blockIdx.x * THREADS + threadIdx.x; i < count; i += gridDim.x * THREADS)
        s += (double)sqrtf(__uint_as_float(bits[i]));
#pragma unroll
    for (int off = 32; off; off >>= 1) s += __shfl_down(s, off, 64);
    __shared__ double sw[4];
    const int lane = threadIdx.x & 63, wid = threadIdx.x >> 6;
    if (lane == 0) sw[wid] = s;
    __syncthreads();
    if (threadIdx.x == 0) partials[blockIdx.x] = sw[0] + sw[1] + sw[2] + sw[3];
}

__global__ __launch_bounds__(THREADS) void cd_reduce2(
    const double* __restrict__ partials, int nb, int total, float* __restrict__ out)
{
    double s = 0.0;
    for (int i = threadIdx.x; i < nb; i += THREADS) s += partials[i];
#pragma unroll
    for (int off = 32; off; off >>= 1) s += __shfl_down(s, off, 64);
    __shared__ double sw[4];
    const int lane = threadIdx.x & 63, wid = threadIdx.x >> 6;
    if (lane == 0) sw[wid] = s;
    __syncthreads();
    if (threadIdx.x == 0)
        out[0] = (float)((sw[0] + sw[1] + sw[2] + sw[3]) / (double)total);
}

extern "C" void kernel_launch(void* const* d_in, const int* in_sizes, int n_in,
                              void* d_out, int out_size, void* d_ws, size_t ws_size,
                              hipStream_t stream) {
    const float* a = (const float*)d_in[0];
    const float* b = (const float*)d_in[1];
    const int n = in_sizes[0] / 3;
    const int m = in_sizes[1] / 3;
    const int total = n + m;
    float* out = (float*)d_out;

    const int padN = (n + QB - 1) / QB * QB;
    const int padM = (m + SLICE - 1) / SLICE * SLICE;
    const int gx  = padN / QB;
    const int nJS = padM / SLICE;

    // ws: Qf | a2 | Sf | bits | partials
    char* wp = (char*)d_ws;
    short8* Qf = (short8*)wp;    wp += (size_t)padN * 32;
    float*  a2 = (float*)wp;     wp += (size_t)padN * 4;
    short8* Sf = (short8*)wp;    wp += (size_t)padM * 32;
    uint32* bits = (uint32*)wp;  wp += (size_t)total * 4;
    wp = (char*)(((size_t)wp + 255) & ~(size_t)255);
    double* partials = (double*)wp;

    const int prepElems = max(max(padN, padM), total);
    cd_prep<<<(prepElems + THREADS - 1) / THREADS, THREADS, 0, stream>>>(
        a, n, padN, b, m, padM, Qf, a2, Sf, bits);

    dim3 grid(gx, nJS);
    cd_mfma<<<grid, THREADS, 0, stream>>>(Qf, a2, padN, n, Sf, padM, m, bits);

    cd_reduce1<<<RB, THREADS, 0, stream>>>(bits, total, partials);
    cd_reduce2<<<1, THREADS, 0, stream>>>(partials, RB, total, out);
}

// Round 20
// 79.492 us; speedup vs baseline: 27.6647x; 2.9381x over previous
//
#include <hip/hip_runtime.h>

typedef unsigned int uint32;
typedef unsigned short ushort16;
typedef __attribute__((ext_vector_type(16))) float f32x16;
typedef __attribute__((ext_vector_type(8)))  short short8;

#define THREADS 256
#define QB 128      // A-rows per block (4 waves x 32)
#define SLICE 512   // B-points per block (16 tiles; 16 KB staging + 8 KB cmlds)
#define RB 128      // reduce stage-1 blocks

__device__ inline ushort16 bf16rn(float x) {
    uint32 u = __float_as_uint(x);
    u += 0x7FFFu + ((u >> 16) & 1u);
    return (ushort16)(u >> 16);
}
__device__ inline float bf2f(ushort16 h) { return __uint_as_float(((uint32)h) << 16); }

// K=16 slot map (verified R11-R19). Row side (A): per coord [h,h,m,m];
// slots 12..14 = 1. Col side (B): per coord [bh,bm,bh,bm] of b=-2c; slots
// 12..14 = 3-level split of |b|^2. C-operand carries |a|^2 =>
// D = |a|^2 + |b|^2 - 2 a.b -> row-min AND col-min both valid, one matrix.
// Pad A rows: a2=1e30 (never win col-min). Pad B cols: s12=1e30 sentinel.
__global__ __launch_bounds__(THREADS) void cd_prep(
    const float* __restrict__ A, int n, int padN,
    const float* __restrict__ B, int m, int padM,
    short8* __restrict__ Qf, float* __restrict__ a2,
    short8* __restrict__ Sf, uint32* __restrict__ bits)
{
    const int i = blockIdx.x * THREADS + threadIdx.x;
    if (i < n + m) bits[i] = 0x7F800000u;  // +inf

    if (i < padN) {  // row side
        ushort16 qs[16];
#pragma unroll
        for (int s = 0; s < 16; ++s) qs[s] = 0;
        float w = 1e30f;
        if (i < n) {
            float c[3] = {A[3*i], A[3*i+1], A[3*i+2]};
            w = fmaf(c[0], c[0], fmaf(c[1], c[1], c[2]*c[2]));
#pragma unroll
            for (int cc = 0; cc < 3; ++cc) {
                ushort16 h = bf16rn(c[cc]);
                ushort16 md = bf16rn(c[cc] - bf2f(h));
                const int b = 4*cc;
                qs[b]=h; qs[b+1]=h; qs[b+2]=md; qs[b+3]=md;
            }
            qs[12]=0x3F80; qs[13]=0x3F80; qs[14]=0x3F80;
        }
        a2[i] = w;
        const int row = i & 31, grp = i >> 5;
#pragma unroll
        for (int h = 0; h < 2; ++h) {
            short8 qv;
#pragma unroll
            for (int e = 0; e < 8; ++e) qv[e] = (short)qs[8*h+e];
            Qf[(size_t)grp*64 + h*32 + row] = qv;
        }
    }
    if (i < padM) {  // col side
        ushort16 ss[16];
#pragma unroll
        for (int s = 0; s < 16; ++s) ss[s] = 0;
        if (i < m) {
            float c[3] = {B[3*i], B[3*i+1], B[3*i+2]};
            float w = fmaf(c[0], c[0], fmaf(c[1], c[1], c[2]*c[2]));
#pragma unroll
            for (int cc = 0; cc < 3; ++cc) {
                float bv = -2.f * c[cc];
                ushort16 bh = bf16rn(bv);
                ushort16 bm = bf16rn(bv - bf2f(bh));
                const int b = 4*cc;
                ss[b]=bh; ss[b+1]=bm; ss[b+2]=bh; ss[b+3]=bm;
            }
            ushort16 wh = bf16rn(w);
            float r1 = w - bf2f(wh);
            ushort16 wm = bf16rn(r1);
            ushort16 wl = bf16rn(r1 - bf2f(wm));
            ss[12]=wh; ss[13]=wm; ss[14]=wl;
        } else {
            ss[12] = bf16rn(1e30f);
        }
        const int row = i & 31, grp = i >> 5;
#pragma unroll
        for (int h = 0; h < 2; ++h) {
            short8 sv;
#pragma unroll
            for (int e = 0; e < 8; ++e) sv[e] = (short)ss[8*h+e];
            Sf[(size_t)grp*64 + h*32 + row] = sv;
        }
    }
}

__device__ inline float dppmin(float v, int ctrl) {
    float s;
    switch (ctrl) {
        case 0xB1:  s = __int_as_float(__builtin_amdgcn_mov_dpp(__float_as_int(v), 0xB1,  0xf, 0xf, false)); break; // xor1
        case 0x4E:  s = __int_as_float(__builtin_amdgcn_mov_dpp(__float_as_int(v), 0x4E,  0xf, 0xf, false)); break; // xor2
        case 0x141: s = __int_as_float(__builtin_amdgcn_mov_dpp(__float_as_int(v), 0x141, 0xf, 0xf, false)); break; // half_mirror
        default:    s = __int_as_float(__builtin_amdgcn_mov_dpp(__float_as_int(v), 0x140, 0xf, 0xf, false)); break; // row_mirror
    }
    return fminf(v, s);
}

// min of 16 regs via min3 tree (~8 ops)
__device__ inline float tmin16(const f32x16& c) {
    float a0 = fminf(fminf(c[0], c[1]), c[2]);
    float a1 = fminf(fminf(c[3], c[4]), c[5]);
    float a2_ = fminf(fminf(c[6], c[7]), c[8]);
    float a3 = fminf(fminf(c[9], c[10]), c[11]);
    float a4 = fminf(fminf(c[12], c[13]), c[14]);
    float b0 = fminf(fminf(a0, a1), c[15]);
    float b1 = fminf(fminf(a2_, a3), a4);
    return fminf(b0, b1);
}

// ONE-PASS chamfer, zero-register col-min. IDENTICAL to R19 except
// launch_bounds(256,2): R17-R19 proved the allocator pins 64 VGPR at (,4)
// and spills the ~90-reg live set through scratch (FETCH 366 MB). (,2)
// lifts the cap; allocator takes ~110, occupancy settles at ~4 waves/SIMD
// (pool 512/SIMD, m69). Per tile: MFMA -> 8 min3 row-fold -> tmin16 ->
// xor32 -> plain LDS store (unique addr, no atomics). End: row butterfly ->
// atomicMin(bits[row]); barrier; 4-way wave-row min -> atomicMin(bits[n+c]).
// C layout (m74/m101): col=lane&31, row=(reg&3)+8*(reg>>2)+4*(lane>>5).
__global__ __launch_bounds__(THREADS, 2) void cd_mfma(
    const short8* __restrict__ Qf, const float* __restrict__ a2, int padN, int n,
    const short8* __restrict__ Sf, int padM, int m,
    uint32* __restrict__ bits)
{
    __shared__ short8 sb[SLICE * 2];        // 16 KB staging
    __shared__ float cmlds[4 * SLICE];      // 8 KB per-wave col-mins

    const int ib = blockIdx.x, js = blockIdx.y;
    const int tid = threadIdx.x, lane = tid & 63, wid = tid >> 6;
    const int qbase = ib * QB + wid * 32;

    const short8 av = Qf[(size_t)(qbase >> 5) * 64 + lane];

    f32x16 pc;
    {
        const int rb = qbase + 4 * (lane >> 5);
#pragma unroll
        for (int r = 0; r < 16; ++r) pc[r] = a2[rb + (r & 3) + 8 * (r >> 2)];
    }

    // stage the slice (1024 short8, 4 per thread), one barrier
    {
        const size_t gb = (size_t)js * (SLICE * 2);
#pragma unroll
        for (int k = 0; k < 4; ++k)
            sb[k * 256 + tid] = Sf[gb + k * 256 + tid];
    }
    __syncthreads();

    float rmin[16];
#pragma unroll
    for (int r = 0; r < 16; ++r) rmin[r] = 1e30f;

    float* myrow = cmlds + wid * SLICE + (lane & 31);
    const bool lo = (lane < 32);

#pragma unroll
    for (int g = 0; g < 8; ++g) {
        const short8 b0 = sb[(2*g)   * 64 + lane];
        const short8 b1 = sb[(2*g+1) * 64 + lane];
        const f32x16 c0 = __builtin_amdgcn_mfma_f32_32x32x16_bf16(av, b0, pc, 0, 0, 0);
        const f32x16 c1 = __builtin_amdgcn_mfma_f32_32x32x16_bf16(av, b1, pc, 0, 0, 0);
#pragma unroll
        for (int r = 0; r < 16; ++r)
            rmin[r] = fminf(fminf(rmin[r], c0[r]), c1[r]);  // v_min3
        float v0 = tmin16(c0);
        float v1 = tmin16(c1);
        v0 = fminf(v0, __shfl_xor(v0, 32, 64));
        v1 = fminf(v1, __shfl_xor(v1, 32, 64));
        if (lo) {
            myrow[(2*g)   * 32] = v0;
            myrow[(2*g+1) * 32] = v1;
        }
    }

    // row-min: butterfly over the 32 cols held across lanes
#pragma unroll
    for (int r = 0; r < 16; ++r) {
        float v = rmin[r];
        v = dppmin(v, 0xB1);
        v = dppmin(v, 0x4E);
        v = dppmin(v, 0x141);
        v = dppmin(v, 0x140);
        v = fminf(v, __shfl_xor(v, 16, 64));
        rmin[r] = v;
    }
    if ((lane & 31) == 0) {
        const int rb = qbase + 4 * (lane >> 5);
#pragma unroll
        for (int r = 0; r < 16; ++r) {
            const int qi = rb + (r & 3) + 8 * (r >> 2);
            if (qi < n)
                atomicMin(&bits[qi], __float_as_uint(fmaxf(rmin[r], 0.f)));
        }
    }

    __syncthreads();   // all cmlds writes visible

#pragma unroll
    for (int u = 0; u < SLICE / THREADS; ++u) {
        const int c = u * THREADS + tid;
        const float v = fminf(fminf(cmlds[c], cmlds[SLICE + c]),
                              fminf(cmlds[2*SLICE + c], cmlds[3*SLICE + c]));
        const int cj = js * SLICE + c;
        if (cj < m)
            atomicMin(&bits[n + cj], __float_as_uint(fmaxf(v, 0.f)));
    }
}

__global__ __launch_bounds__(THREADS) void cd_reduce1(
    const uint32* __restrict__ bits, int count, double* __restrict__ partials)
{
    double s = 0.0;
    for (int i = blockIdx.x * THREADS + threadIdx.x; i < count; i += gridDim.x * THREADS)
        s += (double)sqrtf(__uint_as_float(bits[i]));
#pragma unroll
    for (int off = 32; off; off >>= 1) s += __shfl_down(s, off, 64);
    __shared__ double sw[4];
    const int lane = threadIdx.x & 63, wid = threadIdx.x >> 6;
    if (lane == 0) sw[wid] = s;
    __syncthreads();
    if (threadIdx.x == 0) partials[blockIdx.x] = sw[0] + sw[1] + sw[2] + sw[3];
}

__global__ __launch_bounds__(THREADS) void cd_reduce2(
    const double* __restrict__ partials, int nb, int total, float* __restrict__ out)
{
    double s = 0.0;
    for (int i = threadIdx.x; i < nb; i += THREADS) s += partials[i];
#pragma unroll
    for (int off = 32; off; off >>= 1) s += __shfl_down(s, off, 64);
    __shared__ double sw[4];
    const int lane = threadIdx.x & 63, wid = threadIdx.x >> 6;
    if (lane == 0) sw[wid] = s;
    __syncthreads();
    if (threadIdx.x == 0)
        out[0] = (float)((sw[0] + sw[1] + sw[2] + sw[3]) / (double)total);
}

extern "C" void kernel_launch(void* const* d_in, const int* in_sizes, int n_in,
                              void* d_out, int out_size, void* d_ws, size_t ws_size,
                              hipStream_t stream) {
    const float* a = (const float*)d_in[0];
    const float* b = (const float*)d_in[1];
    const int n = in_sizes[0] / 3;
    const int m = in_sizes[1] / 3;
    const int total = n + m;
    float* out = (float*)d_out;

    const int padN = (n + QB - 1) / QB * QB;
    const int padM = (m + SLICE - 1) / SLICE * SLICE;
    const int gx  = padN / QB;
    const int nJS = padM / SLICE;

    // ws: Qf | a2 | Sf | bits | partials
    char* wp = (char*)d_ws;
    short8* Qf = (short8*)wp;    wp += (size_t)padN * 32;
    float*  a2 = (float*)wp;     wp += (size_t)padN * 4;
    short8* Sf = (short8*)wp;    wp += (size_t)padM * 32;
    uint32* bits = (uint32*)wp;  wp += (size_t)total * 4;
    wp = (char*)(((size_t)wp + 255) & ~(size_t)255);
    double* partials = (double*)wp;

    const int prepElems = max(max(padN, padM), total);
    cd_prep<<<(prepElems + THREADS - 1) / THREADS, THREADS, 0, stream>>>(
        a, n, padN, b, m, padM, Qf, a2, Sf, bits);

    dim3 grid(gx, nJS);
    cd_mfma<<<grid, THREADS, 0, stream>>>(Qf, a2, padN, n, Sf, padM, m, bits);

    cd_reduce1<<<RB, THREADS, 0, stream>>>(bits, total, partials);
    cd_reduce2<<<1, THREADS, 0, stream>>>(partials, RB, total, out);
}

// Round 21
// 50.676 us; speedup vs baseline: 43.3954x; 1.5686x over previous
//
#include <hip/hip_runtime.h>

typedef unsigned int uint32;
typedef unsigned short ushort16;
typedef __attribute__((ext_vector_type(16))) float f32x16;
typedef __attribute__((ext_vector_type(8)))  short short8;

#define THREADS 256
#define QB 128      // A-rows per block (4 waves x 32)
#define SLICE 512   // B-points per block (16 tiles; 16 KB staging + 8 KB cmlds)
#define RB 128      // reduce stage-1 blocks

__device__ inline ushort16 bf16rn(float x) {
    uint32 u = __float_as_uint(x);
    u += 0x7FFFu + ((u >> 16) & 1u);
    return (ushort16)(u >> 16);
}
__device__ inline float bf2f(ushort16 h) { return __uint_as_float(((uint32)h) << 16); }

// K=16 slot map v2 — EVERYTHING in the K-slots, C = 0 (no pc registers):
//   slots 4cc..4cc+3 (cc=0..2):  A:[ah,ah,am,am]  B:[bh,bm,bh,bm]
//        -> (ah+am)(bh+bm) = a_cc * (-2 b_cc) to ~2^-17
//   slots 12,13: A:[a2h,a2m]  B:[1,1]   -> |a|^2 (2-level split)
//   slots 14,15: A:[1,1]      B:[b2h,b2m] -> |b|^2 (2-level split)
// D = |a|^2 + |b|^2 - 2 a.b  => row-min AND col-min valid from one matrix.
// Pad A rows: qs[12]=1e30 (+ qs[14..15]=1) -> never win col-min.
// Pad B cols: ss[14]=1e30, rest 0 -> never win row-min.
__global__ __launch_bounds__(THREADS) void cd_prep(
    const float* __restrict__ A, int n, int padN,
    const float* __restrict__ B, int m, int padM,
    short8* __restrict__ Qf, short8* __restrict__ Sf,
    uint32* __restrict__ bits)
{
    const int i = blockIdx.x * THREADS + threadIdx.x;
    if (i < n + m) bits[i] = 0x7F800000u;  // +inf

    if (i < padN) {  // row side (A)
        ushort16 qs[16];
#pragma unroll
        for (int s = 0; s < 16; ++s) qs[s] = 0;
        if (i < n) {
            float c[3] = {A[3*i], A[3*i+1], A[3*i+2]};
            float w = fmaf(c[0], c[0], fmaf(c[1], c[1], c[2]*c[2]));
#pragma unroll
            for (int cc = 0; cc < 3; ++cc) {
                ushort16 h = bf16rn(c[cc]);
                ushort16 md = bf16rn(c[cc] - bf2f(h));
                const int b = 4*cc;
                qs[b]=h; qs[b+1]=h; qs[b+2]=md; qs[b+3]=md;
            }
            ushort16 wh = bf16rn(w);
            qs[12]=wh; qs[13]=bf16rn(w - bf2f(wh));
            qs[14]=0x3F80; qs[15]=0x3F80;
        } else {
            qs[12]=bf16rn(1e30f);
            qs[14]=0x3F80; qs[15]=0x3F80;
        }
        const int row = i & 31, grp = i >> 5;
#pragma unroll
        for (int h = 0; h < 2; ++h) {
            short8 qv;
#pragma unroll
            for (int e = 0; e < 8; ++e) qv[e] = (short)qs[8*h+e];
            Qf[(size_t)grp*64 + h*32 + row] = qv;
        }
    }
    if (i < padM) {  // col side (B)
        ushort16 ss[16];
#pragma unroll
        for (int s = 0; s < 16; ++s) ss[s] = 0;
        if (i < m) {
            float c[3] = {B[3*i], B[3*i+1], B[3*i+2]};
            float w = fmaf(c[0], c[0], fmaf(c[1], c[1], c[2]*c[2]));
#pragma unroll
            for (int cc = 0; cc < 3; ++cc) {
                float bv = -2.f * c[cc];
                ushort16 bh = bf16rn(bv);
                ushort16 bm = bf16rn(bv - bf2f(bh));
                const int b = 4*cc;
                ss[b]=bh; ss[b+1]=bm; ss[b+2]=bh; ss[b+3]=bm;
            }
            ss[12]=0x3F80; ss[13]=0x3F80;
            ushort16 wh = bf16rn(w);
            ss[14]=wh; ss[15]=bf16rn(w - bf2f(wh));
        } else {
            ss[14] = bf16rn(1e30f);
        }
        const int row = i & 31, grp = i >> 5;
#pragma unroll
        for (int h = 0; h < 2; ++h) {
            short8 sv;
#pragma unroll
            for (int e = 0; e < 8; ++e) sv[e] = (short)ss[8*h+e];
            Sf[(size_t)grp*64 + h*32 + row] = sv;
        }
    }
}

__device__ inline float dppmin(float v, int ctrl) {
    float s;
    switch (ctrl) {
        case 0xB1:  s = __int_as_float(__builtin_amdgcn_mov_dpp(__float_as_int(v), 0xB1,  0xf, 0xf, false)); break; // xor1
        case 0x4E:  s = __int_as_float(__builtin_amdgcn_mov_dpp(__float_as_int(v), 0x4E,  0xf, 0xf, false)); break; // xor2
        case 0x141: s = __int_as_float(__builtin_amdgcn_mov_dpp(__float_as_int(v), 0x141, 0xf, 0xf, false)); break; // half_mirror
        default:    s = __int_as_float(__builtin_amdgcn_mov_dpp(__float_as_int(v), 0x140, 0xf, 0xf, false)); break; // row_mirror
    }
    return fminf(v, s);
}

// min of 16 regs via min3 tree
__device__ inline float tmin16(const f32x16& c) {
    float a0 = fminf(fminf(c[0], c[1]), c[2]);
    float a1 = fminf(fminf(c[3], c[4]), c[5]);
    float a2_ = fminf(fminf(c[6], c[7]), c[8]);
    float a3 = fminf(fminf(c[9], c[10]), c[11]);
    float a4 = fminf(fminf(c[12], c[13]), c[14]);
    float b0 = fminf(fminf(a0, a1), c[15]);
    float b1 = fminf(fminf(a2_, a3), a4);
    return fminf(b0, b1);
}

// ONE-PASS chamfer, minimal register footprint: no pc (a^2 lives in K-slots,
// C = 0), col-min streamed to LDS (no accumulator), unroll bounded to 2 so
// the scheduler can't hoist all 16 ds_reads (R20's spill source). No
// launch_bounds minimum — allocator takes what it needs (~80-110, no spill).
// C layout (m74/m101): col=lane&31, row=(reg&3)+8*(reg>>2)+4*(lane>>5).
__global__ __launch_bounds__(THREADS) void cd_mfma(
    const short8* __restrict__ Qf, int padN, int n,
    const short8* __restrict__ Sf, int padM, int m,
    uint32* __restrict__ bits)
{
    __shared__ short8 sb[SLICE * 2];        // 16 KB staging
    __shared__ float cmlds[4 * SLICE];      // 8 KB per-wave col-mins

    const int ib = blockIdx.x, js = blockIdx.y;
    const int tid = threadIdx.x, lane = tid & 63, wid = tid >> 6;
    const int qbase = ib * QB + wid * 32;

    const short8 av = Qf[(size_t)(qbase >> 5) * 64 + lane];

    // stage the slice (1024 short8, 4 per thread), one barrier
    {
        const size_t gb = (size_t)js * (SLICE * 2);
#pragma unroll
        for (int k = 0; k < 4; ++k)
            sb[k * 256 + tid] = Sf[gb + k * 256 + tid];
    }
    __syncthreads();

    float rmin[16];
#pragma unroll
    for (int r = 0; r < 16; ++r) rmin[r] = 1e30f;

    const f32x16 zero = {0.f,0.f,0.f,0.f,0.f,0.f,0.f,0.f,
                         0.f,0.f,0.f,0.f,0.f,0.f,0.f,0.f};

    float* myrow = cmlds + wid * SLICE + (lane & 31);
    const bool lo = (lane < 32);

#pragma unroll 2
    for (int g = 0; g < 8; ++g) {
        const short8 b0 = sb[(2*g)   * 64 + lane];
        const short8 b1 = sb[(2*g+1) * 64 + lane];
        const f32x16 c0 = __builtin_amdgcn_mfma_f32_32x32x16_bf16(av, b0, zero, 0, 0, 0);
        const f32x16 c1 = __builtin_amdgcn_mfma_f32_32x32x16_bf16(av, b1, zero, 0, 0, 0);
#pragma unroll
        for (int r = 0; r < 16; ++r)
            rmin[r] = fminf(fminf(rmin[r], c0[r]), c1[r]);  // v_min3
        float v0 = tmin16(c0);
        float v1 = tmin16(c1);
        v0 = fminf(v0, __shfl_xor(v0, 32, 64));
        v1 = fminf(v1, __shfl_xor(v1, 32, 64));
        if (lo) {
            myrow[(2*g)   * 32] = v0;
            myrow[(2*g+1) * 32] = v1;
        }
    }

    // row-min: butterfly over the 32 cols held across lanes
#pragma unroll
    for (int r = 0; r < 16; ++r) {
        float v = rmin[r];
        v = dppmin(v, 0xB1);
        v = dppmin(v, 0x4E);
        v = dppmin(v, 0x141);
        v = dppmin(v, 0x140);
        v = fminf(v, __shfl_xor(v, 16, 64));
        rmin[r] = v;
    }
    if ((lane & 31) == 0) {
        const int rb = qbase + 4 * (lane >> 5);
#pragma unroll
        for (int r = 0; r < 16; ++r) {
            const int qi = rb + (r & 3) + 8 * (r >> 2);
            if (qi < n)
                atomicMin(&bits[qi], __float_as_uint(fmaxf(rmin[r], 0.f)));
        }
    }

    __syncthreads();   // all cmlds writes visible

#pragma unroll
    for (int u = 0; u < SLICE / THREADS; ++u) {
        const int c = u * THREADS + tid;
        const float v = fminf(fminf(cmlds[c], cmlds[SLICE + c]),
                              fminf(cmlds[2*SLICE + c], cmlds[3*SLICE + c]));
        const int cj = js * SLICE + c;
        if (cj < m)
            atomicMin(&bits[n + cj], __float_as_uint(fmaxf(v, 0.f)));
    }
}

__global__ __launch_bounds__(THREADS) void cd_reduce1(
    const uint32* __restrict__ bits, int count, double* __restrict__ partials)
{
    double s = 0.0;
    for (int i = blockIdx.x * THREADS + threadIdx.x; i < count; i += gridDim.x * THREADS)
        s += (double)sqrtf(__uint_as_float(bits[i]));
#pragma unroll
    for (int off = 32; off; off >>= 1) s += __shfl_down(s, off, 64);
    __shared__ double sw[4];
    const int lane = threadIdx.x & 63, wid = threadIdx.x >> 6;
    if (lane == 0) sw[wid] = s;
    __syncthreads();
    if (threadIdx.x == 0) partials[blockIdx.x] = sw[0] + sw[1] + sw[2] + sw[3];
}

__global__ __launch_bounds__(THREADS) void cd_reduce2(
    const double* __restrict__ partials, int nb, int total, float* __restrict__ out)
{
    double s = 0.0;
    for (int i = threadIdx.x; i < nb; i += THREADS) s += partials[i];
#pragma unroll
    for (int off = 32; off; off >>= 1) s += __shfl_down(s, off, 64);
    __shared__ double sw[4];
    const int lane = threadIdx.x & 63, wid = threadIdx.x >> 6;
    if (lane == 0) sw[wid] = s;
    __syncthreads();
    if (threadIdx.x == 0)
        out[0] = (float)((sw[0] + sw[1] + sw[2] + sw[3]) / (double)total);
}

extern "C" void kernel_launch(void* const* d_in, const int* in_sizes, int n_in,
                              void* d_out, int out_size, void* d_ws, size_t ws_size,
                              hipStream_t stream) {
    const float* a = (const float*)d_in[0];
    const float* b = (const float*)d_in[1];
    const int n = in_sizes[0] / 3;
    const int m = in_sizes[1] / 3;
    const int total = n + m;
    float* out = (float*)d_out;

    const int padN = (n + QB - 1) / QB * QB;
    const int padM = (m + SLICE - 1) / SLICE * SLICE;
    const int gx  = padN / QB;
    const int nJS = padM / SLICE;

    // ws: Qf | Sf | bits | partials
    char* wp = (char*)d_ws;
    short8* Qf = (short8*)wp;    wp += (size_t)padN * 32;
    short8* Sf = (short8*)wp;    wp += (size_t)padM * 32;
    uint32* bits = (uint32*)wp;  wp += (size_t)total * 4;
    wp = (char*)(((size_t)wp + 255) & ~(size_t)255);
    double* partials = (double*)wp;

    const int prepElems = max(max(padN, padM), total);
    cd_prep<<<(prepElems + THREADS - 1) / THREADS, THREADS, 0, stream>>>(
        a, n, padN, b, m, padM, Qf, Sf, bits);

    dim3 grid(gx, nJS);
    cd_mfma<<<grid, THREADS, 0, stream>>>(Qf, padN, n, Sf, padM, m, bits);

    cd_reduce1<<<RB, THREADS, 0, stream>>>(bits, total, partials);
    cd_reduce2<<<1, THREADS, 0, stream>>>(partials, RB, total, out);
}